// Round 6
// baseline (355.153 us; speedup 1.0000x reference)
//
#include <hip/hip_runtime.h>

// RT-DETRv2 multiscale deformable attention, MI355X/gfx950.
// B=16, Q=300, S=8400 (80x80+40x40+20x20), D=256, H=8, HD=32, L=3, P=4, LP=12.
// Inputs fp32, output fp32 (verified; absmax 1.2e-3 vs thr 2.7e-3).
//
//   K0 prep:      pre-swizzle weights fp32->bf16 into B-fragment order
//   K1 gemm_nt<2>: value = enc @ w_value^T + b     -> ws bf16 [b][s][h][32]
//                  (barrier-free: B frags straight from L2, no LDS)
//   K2 proj_gemm: MFMA logits + fused softmax/loc  -> ws attnw/locw fp32
//   K3 sample:    precomputed-corner gather + sum  -> ws sampled bf16
//   K4 gemm_nt<1>: out = sampled @ w_out^T + b_out -> d_out fp32

typedef __attribute__((ext_vector_type(8))) short short8;   // MFMA A/B frag (8 bf16)
typedef __attribute__((ext_vector_type(4))) float f32x4;    // MFMA accumulator

__device__ __forceinline__ unsigned short f2bf(float f) {   // fp32 -> bf16 RTNE
    union { float f; unsigned int i; } v; v.f = f;
    unsigned int r = v.i + 0x7FFFu + ((v.i >> 16) & 1u);
    return (unsigned short)(r >> 16);
}
__device__ __forceinline__ float bf2f(unsigned short u) {
    union { unsigned int i; float f; } v;
    v.i = ((unsigned int)u) << 16;
    return v.f;
}
__device__ __forceinline__ short8 cvt8(const float* p) {
    f32x4 x = *(const f32x4*)p;
    f32x4 y = *(const f32x4*)(p + 4);
    short8 r;
#pragma unroll
    for (int q = 0; q < 4; ++q) {
        r[q]     = (short)f2bf(x[q]);
        r[q + 4] = (short)f2bf(y[q]);
    }
    return r;
}

// ---- K0: pre-swizzle weights into B-fragment order (bf16) ------------------
// Slot s = kcb*1024 + tile*64 + fragLane holds
// W[n = tile*16 + (fl&15)][kcb*32 + (fl>>4)*8 .. +8).  Proj W: 18 n-tiles
// (288 rows = w_off ++ w_attn), 1152 slots/kcb.
__global__ __launch_bounds__(256) void prep_kernel(
    const float* __restrict__ wv, const float* __restrict__ wo,
    const float* __restrict__ w_off, const float* __restrict__ w_attn,
    short8* __restrict__ wv_s, short8* __restrict__ wo_s, short8* __restrict__ wp_s)
{
    const int blk = blockIdx.x, tid = threadIdx.x;
    if (blk < 64) {
        const float* W = (blk < 32) ? wv : wo;
        short8* out    = (blk < 32) ? wv_s : wo_s;
        int s   = ((blk & 31) << 8) + tid;
        int kcb = s >> 10, sl = s & 1023;
        int n = ((sl >> 6) << 4) + (sl & 15);
        int k = (kcb << 5) + (((sl >> 4) & 3) << 3);
        out[s] = cvt8(W + n * 256 + k);
    } else {
        int s   = ((blk - 64) << 8) + tid;
        int kcb = s / 1152, sl = s - kcb * 1152;
        int n = ((sl >> 6) << 4) + (sl & 15);
        int k = (kcb << 5) + (((sl >> 4) & 3) << 3);
        const float* p = (n < 192) ? (w_off + (size_t)n * 256 + k)
                                   : (w_attn + (size_t)(n - 192) * 256 + k);
        wp_s[s] = cvt8(p);
    }
}

// ---- K1/K4: C[M x 256] = A[M x 256] @ W^T + bias ---------------------------
// Barrier-free: B fragments are read per-iteration straight from the
// pre-swizzled global W (128 KB, L2-resident & shared by all blocks) with
// perfectly coalesced 16B/lane loads. No LDS, no __syncthreads -> waves are
// independent streams; fine-grained vmcnt scheduling is left to the compiler.
// RPW row-fragments per wave amortize the 16 b-loads over 16*RPW MFMAs.
template <int RPW, bool A_BF16, bool OUT_BF16>
__global__ __launch_bounds__(256) void gemm_nt(
    const void* __restrict__ Av,
    const short8* __restrict__ Wswz,
    const float* __restrict__ bias,
    void* __restrict__ Cv)
{
    const int tid  = threadIdx.x;
    const int wave = tid >> 6;
    const int lane = tid & 63;
    const int row0 = blockIdx.x * (64 * RPW) + wave * (16 * RPW);

    f32x4 acc[RPW][16];
#pragma unroll
    for (int r = 0; r < RPW; ++r)
#pragma unroll
        for (int t = 0; t < 16; ++t) acc[r][t] = (f32x4){0.f, 0.f, 0.f, 0.f};

    const int am = row0 + (lane & 15);   // first A row for this lane
    const int kq = (lane >> 4) << 3;     // k sub-offset within 32-chunk

    for (int kcb = 0; kcb < 8; ++kcb) {
        short8 a[RPW];
#pragma unroll
        for (int r = 0; r < RPW; ++r) {
            if (A_BF16)
                a[r] = *(const short8*)((const unsigned short*)Av
                        + (size_t)(am + 16 * r) * 256 + (kcb << 5) + kq);
            else
                a[r] = cvt8((const float*)Av + (size_t)(am + 16 * r) * 256 + (kcb << 5) + kq);
        }
        const short8* wp = Wswz + (kcb << 10) + lane;
#pragma unroll
        for (int t = 0; t < 16; ++t) {
            short8 b = wp[t * 64];       // wave reads contiguous 1KB, L2-hot
#pragma unroll
            for (int r = 0; r < RPW; ++r)
                acc[r][t] = __builtin_amdgcn_mfma_f32_16x16x32_bf16(a[r], b, acc[r][t], 0, 0, 0);
        }
    }

    // epilogue: D[row][col], col = lane&15, row = rowgroup + (lane>>4)*4 + reg
    const int ncol = lane & 15;
#pragma unroll
    for (int r = 0; r < RPW; ++r) {
        const int rb = row0 + r * 16 + ((lane >> 4) << 2);
#pragma unroll
        for (int t = 0; t < 16; ++t) {
            int n = (t << 4) + ncol;
            float bv = bias[n];
#pragma unroll
            for (int rr = 0; rr < 4; ++rr) {
                float v = acc[r][t][rr] + bv;
                if (OUT_BF16)
                    ((unsigned short*)Cv)[(size_t)(rb + rr) * 256 + n] = f2bf(v);
                else
                    ((float*)Cv)[(size_t)(rb + rr) * 256 + n] = v;
            }
        }
    }
}

// ---- K2: proj logits (MFMA) + fused softmax + sample locations -------------
#define LGS 296   // padded LDS row stride (floats)
__global__ __launch_bounds__(256) void proj_gemm(
    const float* __restrict__ hidden,
    const short8* __restrict__ Wswz,
    const float* __restrict__ b_off, const float* __restrict__ b_attn,
    const float* __restrict__ refp,
    float* __restrict__ attnw, float* __restrict__ locw)
{
    __shared__ char smem[32 * LGS * 4];               // >= 1152*16 staging
    short8* lb = (short8*)smem;
    float*  lg = (float*)smem;

    const int tid  = threadIdx.x;
    const int wave = tid >> 6;
    const int lane = tid & 63;
    const int rq0  = blockIdx.x * 32;
    const int rg   = wave >> 1;
    const int ts   = (wave & 1) * 9;
    const int row0 = rq0 + rg * 16;

    f32x4 acc[9];
#pragma unroll
    for (int t = 0; t < 9; ++t) acc[t] = (f32x4){0.f, 0.f, 0.f, 0.f};

    const int am = row0 + (lane & 15);
    const int kq = (lane >> 4) << 3;

    for (int kcb = 0; kcb < 8; ++kcb) {
        __syncthreads();
#pragma unroll
        for (int i = 0; i < 5; ++i) {
            int s = tid + (i << 8);
            if (s < 1152) lb[s] = Wswz[kcb * 1152 + s];
        }
        __syncthreads();

        short8 a = cvt8(hidden + (size_t)am * 256 + (kcb << 5) + kq);
#pragma unroll
        for (int t = 0; t < 9; ++t)
            acc[t] = __builtin_amdgcn_mfma_f32_16x16x32_bf16(a, lb[(ts + t) * 64 + lane], acc[t], 0, 0, 0);
    }

    __syncthreads();
    const int ncol = lane & 15;
    const int rb   = rg * 16 + ((lane >> 4) << 2);
#pragma unroll
    for (int t = 0; t < 9; ++t) {
        int n = (ts + t) * 16 + ncol;
        float bv = (n < 192) ? b_off[n] : b_attn[n - 192];
#pragma unroll
        for (int r = 0; r < 4; ++r)
            lg[(rb + r) * LGS + n] = acc[t][r] + bv;
    }
    __syncthreads();

    {   // softmax: 32 rows x 8 heads, one per thread
        int r = tid >> 3, h = tid & 7;
        const float* lrow = lg + r * LGS + 192 + h * 12;
        float m = -1e30f;
#pragma unroll
        for (int p = 0; p < 12; ++p) m = fmaxf(m, lrow[p]);
        float e[12], sum = 0.f;
#pragma unroll
        for (int p = 0; p < 12; ++p) { e[p] = __expf(lrow[p] - m); sum += e[p]; }
        float inv = 1.f / sum;
        float* ao = attnw + (size_t)(rq0 + r) * 96 + h * 12;
#pragma unroll
        for (int p = 0; p < 12; ++p) ao[p] = e[p] * inv;
    }
    if (tid < 192) {   // loc = ref_xy + logit*0.125*ref_wh
        int xy = tid & 1;
        for (int r = 0; r < 32; ++r) {
            int rq = rq0 + r;
            float rc  = refp[(size_t)rq * 4 + xy];
            float rwh = refp[(size_t)rq * 4 + 2 + xy];
            locw[(size_t)rq * 192 + tid] = rc + lg[r * LGS + tid] * 0.125f * rwh;
        }
    }
}

// ---- K3: deformable bilinear sampling --------------------------------------
// Phase 1 (96 threads): per (h,point) compute 4 clamped corner offsets +
// combined weights aw*wy*wx*valid -> LDS.  Phase 2: pure gather+fma, 48
// independent loads/thread; offsets broadcast from LDS.
__global__ __launch_bounds__(256) void sample_kernel(
    const unsigned short* __restrict__ value,   // bf16 [b][s][h][32]
    const float* __restrict__ attnw, const float* __restrict__ locw,
    unsigned short* __restrict__ sampled)       // bf16 [rq][256]
{
    const int rq  = blockIdx.x;
    const int b   = rq / 300;
    const int tid = threadIdx.x;

    __shared__ int4   soff[96];
    __shared__ float4 swt[96];

    if (tid < 96) {
        int h = tid / 12, lp = tid - h * 12;
        int l = lp >> 2;
        int Wl = (l == 0) ? 80 : (l == 1) ? 40 : 20;        // H == W per level
        int s0 = (l == 0) ? 0  : (l == 1) ? 6400 : 8000;
        float lx = locw[(size_t)rq * 192 + h * 24 + lp * 2];
        float ly = locw[(size_t)rq * 192 + h * 24 + lp * 2 + 1];
        float aw = attnw[(size_t)rq * 96 + h * 12 + lp];
        float gx = lx * (float)Wl - 0.5f;
        float gy = ly * (float)Wl - 0.5f;
        float x0f = floorf(gx), y0f = floorf(gy);
        int   x0 = (int)x0f,   y0 = (int)y0f;
        float wx1 = gx - x0f, wx0 = 1.f - wx1;
        float wy1 = gy - y0f, wy0 = 1.f - wy1;
        int4 of; float4 wt;
#pragma unroll
        for (int j = 0; j < 4; ++j) {
            int x = x0 + (j & 1), y = y0 + (j >> 1);
            bool ok = (x >= 0) & (x < Wl) & (y >= 0) & (y < Wl);
            int idx = ok ? (((b * 8400 + s0 + y * Wl + x) * 8 + h) * 32) : 0;
            float w = ok ? aw * ((j & 1) ? wx1 : wx0) * ((j >> 1) ? wy1 : wy0) : 0.f;
            ((int*)&of)[j] = idx;
            ((float*)&wt)[j] = w;
        }
        soff[tid] = of;
        swt[tid]  = wt;
    }
    __syncthreads();

    const int h = tid >> 5, c = tid & 31;
    float acc = 0.f;
#pragma unroll
    for (int lp = 0; lp < 12; ++lp) {
        int idx = h * 12 + lp;
        int4   of = soff[idx];
        float4 wt = swt[idx];
        acc += wt.x * bf2f(value[of.x + c]);
        acc += wt.y * bf2f(value[of.y + c]);
        acc += wt.z * bf2f(value[of.z + c]);
        acc += wt.w * bf2f(value[of.w + c]);
    }
    sampled[(size_t)rq * 256 + tid] = f2bf(acc);
}

extern "C" void kernel_launch(void* const* d_in, const int* in_sizes, int n_in,
                              void* d_out, int out_size, void* d_ws, size_t ws_size,
                              hipStream_t stream)
{
    const float* hidden  = (const float*)d_in[0];
    const float* enc     = (const float*)d_in[1];
    const float* refp    = (const float*)d_in[2];
    const float* w_value = (const float*)d_in[3];
    const float* b_value = (const float*)d_in[4];
    const float* w_off   = (const float*)d_in[5];
    const float* b_off   = (const float*)d_in[6];
    const float* w_attn  = (const float*)d_in[7];
    const float* b_attn  = (const float*)d_in[8];
    const float* w_out   = (const float*)d_in[9];
    const float* b_out   = (const float*)d_in[10];

    // ws layout: value 68,812,800 | sampled 2,457,600 | attnw 1,843,200 |
    // locw 3,686,400 | wv_swz 131,072 | wo_swz 131,072 | wp_swz 147,456
    char* ws = (char*)d_ws;
    unsigned short* value   = (unsigned short*)ws;
    unsigned short* sampled = (unsigned short*)(ws + 68812800);
    float*          attnw   = (float*)(ws + 71270400);
    float*          locw    = (float*)(ws + 73113600);
    short8*         wv_swz  = (short8*)(ws + 76800000);
    short8*         wo_swz  = (short8*)(ws + 76931072);
    short8*         wp_swz  = (short8*)(ws + 77062144);

    prep_kernel<<<100, 256, 0, stream>>>(w_value, w_out, w_off, w_attn,        // K0
                                         wv_swz, wo_swz, wp_swz);
    gemm_nt<2, false, true><<<1050, 256, 0, stream>>>(enc, wv_swz, b_value,    // K1
                                                      value);
    proj_gemm<<<150, 256, 0, stream>>>(hidden, wp_swz, b_off, b_attn,          // K2
                                       refp, attnw, locw);
    sample_kernel<<<4800, 256, 0, stream>>>(value, attnw, locw, sampled);      // K3
    gemm_nt<1, true, false><<<75, 256, 0, stream>>>(sampled, wo_swz, b_out,    // K4
                                                    d_out);
}

// Round 7
// 298.706 us; speedup vs baseline: 1.1890x; 1.1890x over previous
//
#include <hip/hip_runtime.h>

// RT-DETRv2 multiscale deformable attention, MI355X/gfx950.
// B=16, Q=300, S=8400 (80x80+40x40+20x20), D=256, H=8, HD=32, L=3, P=4, LP=12.
// Inputs fp32, output fp32 (verified; absmax 1.2e-3 vs thr 2.7e-3).
//
//   K0 prep:      pre-swizzle weights fp32->bf16 into B-fragment order
//   K1 gemm_nt:   value = enc @ w_value^T + b     -> ws bf16 [b][s][h][32]
//                 (R4 LDS structure + BK=64 + A-prefetch over raw barriers)
//   K2 proj_gemm: MFMA logits + fused softmax/loc -> ws attnw/locw fp32
//   K3 sample:    precomputed-corner gather + sum -> ws sampled bf16
//   K4 gemm_nt:   out = sampled @ w_out^T + b_out -> d_out fp32
//
// Register-budget law (measured R4-R6): acc 16 tiles = 64 AGPR; keeping
// VGPR+AGPR <= ~170 holds 3 waves/SIMD. RPW=2 (276 regs -> 1 wave/SIMD)
// regressed 83->121/137 us. Do NOT widen the accumulator.

typedef __attribute__((ext_vector_type(8))) short short8;   // MFMA A/B frag (8 bf16)
typedef __attribute__((ext_vector_type(4))) float f32x4;    // MFMA accumulator

__device__ __forceinline__ unsigned short f2bf(float f) {   // fp32 -> bf16 RTNE
    union { float f; unsigned int i; } v; v.f = f;
    unsigned int r = v.i + 0x7FFFu + ((v.i >> 16) & 1u);
    return (unsigned short)(r >> 16);
}
__device__ __forceinline__ float bf2f(unsigned short u) {
    union { unsigned int i; float f; } v;
    v.i = ((unsigned int)u) << 16;
    return v.f;
}
__device__ __forceinline__ short8 cvt8(const float* p) {
    f32x4 x = *(const f32x4*)p;
    f32x4 y = *(const f32x4*)(p + 4);
    short8 r;
#pragma unroll
    for (int q = 0; q < 4; ++q) {
        r[q]     = (short)f2bf(x[q]);
        r[q + 4] = (short)f2bf(y[q]);
    }
    return r;
}
// Publish LDS + workgroup barrier WITHOUT draining vmcnt: keeps A-prefetch
// global loads in flight across the barrier (the m97-class vmcnt(0) drain is
// what we're deleting). ds ops are waited (lgkmcnt 0); "memory" clobber stops
// compiler reordering of memory ops across the barrier.
__device__ __forceinline__ void barrier_lgkm() {
    asm volatile("s_waitcnt lgkmcnt(0)\n\ts_barrier" ::: "memory");
}

// ---- K0: pre-swizzle weights into B-fragment order (bf16) ------------------
// Slot s = kcb*1024 + tile*64 + fragLane holds
// W[n = tile*16 + (fl&15)][kcb*32 + (fl>>4)*8 .. +8).  Proj W: 18 n-tiles
// (288 rows = w_off ++ w_attn), 1152 slots/kcb.
__global__ __launch_bounds__(256) void prep_kernel(
    const float* __restrict__ wv, const float* __restrict__ wo,
    const float* __restrict__ w_off, const float* __restrict__ w_attn,
    short8* __restrict__ wv_s, short8* __restrict__ wo_s, short8* __restrict__ wp_s)
{
    const int blk = blockIdx.x, tid = threadIdx.x;
    if (blk < 64) {
        const float* W = (blk < 32) ? wv : wo;
        short8* out    = (blk < 32) ? wv_s : wo_s;
        int s   = ((blk & 31) << 8) + tid;
        int kcb = s >> 10, sl = s & 1023;
        int n = ((sl >> 6) << 4) + (sl & 15);
        int k = (kcb << 5) + (((sl >> 4) & 3) << 3);
        out[s] = cvt8(W + n * 256 + k);
    } else {
        int s   = ((blk - 64) << 8) + tid;
        int kcb = s / 1152, sl = s - kcb * 1152;
        int n = ((sl >> 6) << 4) + (sl & 15);
        int k = (kcb << 5) + (((sl >> 4) & 3) << 3);
        const float* p = (n < 192) ? (w_off + (size_t)n * 256 + k)
                                   : (w_attn + (size_t)(n - 192) * 256 + k);
        wp_s[s] = cvt8(p);
    }
}

// ---- K1/K4: C[M x 256] = A[M x 256] @ W^T + bias ---------------------------
// 256 thr = 4 waves; block tile 64 rows x 256 cols; wave owns 16 rows.
// K-loop: 4 stages of BK=64 (two kcb per stage; 8 barriers/block, was 16).
// W staged in LDS (pre-swizzled, L2-hot copy). A fragments for stage s+1 are
// loaded before stage-s compute and ride across the raw barriers (no vmcnt
// drain) so their HBM latency hides under stage-s ds_read+MFMA.
template <bool A_BF16, bool OUT_BF16>
__global__ __launch_bounds__(256) void gemm_nt(
    const void* __restrict__ Av,
    const short8* __restrict__ Wswz,
    const float* __restrict__ bias,
    void* __restrict__ Cv)
{
    __shared__ short8 lb[2048];   // 32 KiB: 2 kcb x 1024 slots
    const int tid  = threadIdx.x;
    const int wave = tid >> 6;
    const int lane = tid & 63;
    const int row0 = blockIdx.x * 64 + wave * 16;

    f32x4 acc[16];
#pragma unroll
    for (int t = 0; t < 16; ++t) acc[t] = (f32x4){0.f, 0.f, 0.f, 0.f};

    const int am = row0 + (lane & 15);   // A row for this lane's fragment
    const int kq = (lane >> 4) << 3;     // k sub-offset within 32-chunk

    const unsigned short* Ab = (const unsigned short*)Av;
    const float*          Af = (const float*)Av;

    short8 acur[2], anext[2];
#pragma unroll
    for (int kk = 0; kk < 2; ++kk) {     // prologue: stage-0 A fragments
        if (A_BF16) acur[kk] = *(const short8*)(Ab + (size_t)am * 256 + (kk << 5) + kq);
        else        acur[kk] = cvt8(Af + (size_t)am * 256 + (kk << 5) + kq);
    }

    for (int st = 0; st < 4; ++st) {
        barrier_lgkm();   // all waves done reading previous stage's LDS
        // stage W for kcb = 2*st, 2*st+1: contiguous copy, 8 slots/thread
#pragma unroll
        for (int i = 0; i < 8; ++i) {
            int s = tid + (i << 8);
            lb[s] = Wswz[(st << 11) + s];   // L2-hot; vmcnt waits are per-ds_write data deps
        }
        barrier_lgkm();   // LDS published; A-prefetch loads still in flight

        if (st < 3) {     // prefetch next stage's A fragments (consumed next iter)
            int kc = (st + 1) << 6;
#pragma unroll
            for (int kk = 0; kk < 2; ++kk) {
                if (A_BF16) anext[kk] = *(const short8*)(Ab + (size_t)am * 256 + kc + (kk << 5) + kq);
                else        anext[kk] = cvt8(Af + (size_t)am * 256 + kc + (kk << 5) + kq);
            }
        }

#pragma unroll
        for (int t = 0; t < 16; ++t) {
            short8 b0 = lb[t * 64 + lane];
            acc[t] = __builtin_amdgcn_mfma_f32_16x16x32_bf16(acur[0], b0, acc[t], 0, 0, 0);
            short8 b1 = lb[1024 + t * 64 + lane];
            acc[t] = __builtin_amdgcn_mfma_f32_16x16x32_bf16(acur[1], b1, acc[t], 0, 0, 0);
        }
        acur[0] = anext[0];
        acur[1] = anext[1];
    }

    // epilogue: D[row][col], col = lane&15, row = (lane>>4)*4 + reg
    const int ncol = lane & 15;
    const int rb   = row0 + ((lane >> 4) << 2);
#pragma unroll
    for (int t = 0; t < 16; ++t) {
        int n = (t << 4) + ncol;
        float bv = bias[n];
#pragma unroll
        for (int r = 0; r < 4; ++r) {
            float v = acc[t][r] + bv;
            if (OUT_BF16)
                ((unsigned short*)Cv)[(size_t)(rb + r) * 256 + n] = f2bf(v);
            else
                ((float*)Cv)[(size_t)(rb + r) * 256 + n] = v;
        }
    }
}

// ---- K2: proj logits (MFMA) + fused softmax + sample locations -------------
#define LGS 296   // padded LDS row stride (floats)
__global__ __launch_bounds__(256) void proj_gemm(
    const float* __restrict__ hidden,
    const short8* __restrict__ Wswz,
    const float* __restrict__ b_off, const float* __restrict__ b_attn,
    const float* __restrict__ refp,
    float* __restrict__ attnw, float* __restrict__ locw)
{
    __shared__ char smem[32 * LGS * 4];               // >= 1152*16 staging
    short8* lb = (short8*)smem;
    float*  lg = (float*)smem;

    const int tid  = threadIdx.x;
    const int wave = tid >> 6;
    const int lane = tid & 63;
    const int rq0  = blockIdx.x * 32;
    const int rg   = wave >> 1;
    const int ts   = (wave & 1) * 9;
    const int row0 = rq0 + rg * 16;

    f32x4 acc[9];
#pragma unroll
    for (int t = 0; t < 9; ++t) acc[t] = (f32x4){0.f, 0.f, 0.f, 0.f};

    const int am = row0 + (lane & 15);
    const int kq = (lane >> 4) << 3;

    for (int kcb = 0; kcb < 8; ++kcb) {
        __syncthreads();
#pragma unroll
        for (int i = 0; i < 5; ++i) {
            int s = tid + (i << 8);
            if (s < 1152) lb[s] = Wswz[kcb * 1152 + s];
        }
        __syncthreads();

        short8 a = cvt8(hidden + (size_t)am * 256 + (kcb << 5) + kq);
#pragma unroll
        for (int t = 0; t < 9; ++t)
            acc[t] = __builtin_amdgcn_mfma_f32_16x16x32_bf16(a, lb[(ts + t) * 64 + lane], acc[t], 0, 0, 0);
    }

    __syncthreads();
    const int ncol = lane & 15;
    const int rb   = rg * 16 + ((lane >> 4) << 2);
#pragma unroll
    for (int t = 0; t < 9; ++t) {
        int n = (ts + t) * 16 + ncol;
        float bv = (n < 192) ? b_off[n] : b_attn[n - 192];
#pragma unroll
        for (int r = 0; r < 4; ++r)
            lg[(rb + r) * LGS + n] = acc[t][r] + bv;
    }
    __syncthreads();

    {   // softmax: 32 rows x 8 heads, one per thread
        int r = tid >> 3, h = tid & 7;
        const float* lrow = lg + r * LGS + 192 + h * 12;
        float m = -1e30f;
#pragma unroll
        for (int p = 0; p < 12; ++p) m = fmaxf(m, lrow[p]);
        float e[12], sum = 0.f;
#pragma unroll
        for (int p = 0; p < 12; ++p) { e[p] = __expf(lrow[p] - m); sum += e[p]; }
        float inv = 1.f / sum;
        float* ao = attnw + (size_t)(rq0 + r) * 96 + h * 12;
#pragma unroll
        for (int p = 0; p < 12; ++p) ao[p] = e[p] * inv;
    }
    if (tid < 192) {   // loc = ref_xy + logit*0.125*ref_wh
        int xy = tid & 1;
        for (int r = 0; r < 32; ++r) {
            int rq = rq0 + r;
            float rc  = refp[(size_t)rq * 4 + xy];
            float rwh = refp[(size_t)rq * 4 + 2 + xy];
            locw[(size_t)rq * 192 + tid] = rc + lg[r * LGS + tid] * 0.125f * rwh;
        }
    }
}

// ---- K3: deformable bilinear sampling --------------------------------------
// Phase 1 (96 threads): per (h,point) compute 4 clamped corner offsets +
// combined weights aw*wy*wx*valid -> LDS.  Phase 2: pure gather+fma, 48
// independent loads/thread; offsets broadcast from LDS.
__global__ __launch_bounds__(256) void sample_kernel(
    const unsigned short* __restrict__ value,   // bf16 [b][s][h][32]
    const float* __restrict__ attnw, const float* __restrict__ locw,
    unsigned short* __restrict__ sampled)       // bf16 [rq][256]
{
    const int rq  = blockIdx.x;
    const int b   = rq / 300;
    const int tid = threadIdx.x;

    __shared__ int4   soff[96];
    __shared__ float4 swt[96];

    if (tid < 96) {
        int h = tid / 12, lp = tid - h * 12;
        int l = lp >> 2;
        int Wl = (l == 0) ? 80 : (l == 1) ? 40 : 20;        // H == W per level
        int s0 = (l == 0) ? 0  : (l == 1) ? 6400 : 8000;
        float lx = locw[(size_t)rq * 192 + h * 24 + lp * 2];
        float ly = locw[(size_t)rq * 192 + h * 24 + lp * 2 + 1];
        float aw = attnw[(size_t)rq * 96 + h * 12 + lp];
        float gx = lx * (float)Wl - 0.5f;
        float gy = ly * (float)Wl - 0.5f;
        float x0f = floorf(gx), y0f = floorf(gy);
        int   x0 = (int)x0f,   y0 = (int)y0f;
        float wx1 = gx - x0f, wx0 = 1.f - wx1;
        float wy1 = gy - y0f, wy0 = 1.f - wy1;
        int4 of; float4 wt;
#pragma unroll
        for (int j = 0; j < 4; ++j) {
            int x = x0 + (j & 1), y = y0 + (j >> 1);
            bool ok = (x >= 0) & (x < Wl) & (y >= 0) & (y < Wl);
            int idx = ok ? (((b * 8400 + s0 + y * Wl + x) * 8 + h) * 32) : 0;
            float w = ok ? aw * ((j & 1) ? wx1 : wx0) * ((j >> 1) ? wy1 : wy0) : 0.f;
            ((int*)&of)[j] = idx;
            ((float*)&wt)[j] = w;
        }
        soff[tid] = of;
        swt[tid]  = wt;
    }
    __syncthreads();

    const int h = tid >> 5, c = tid & 31;
    float acc = 0.f;
#pragma unroll
    for (int lp = 0; lp < 12; ++lp) {
        int idx = h * 12 + lp;
        int4   of = soff[idx];
        float4 wt = swt[idx];
        acc += wt.x * bf2f(value[of.x + c]);
        acc += wt.y * bf2f(value[of.y + c]);
        acc += wt.z * bf2f(value[of.z + c]);
        acc += wt.w * bf2f(value[of.w + c]);
    }
    sampled[(size_t)rq * 256 + tid] = f2bf(acc);
}

extern "C" void kernel_launch(void* const* d_in, const int* in_sizes, int n_in,
                              void* d_out, int out_size, void* d_ws, size_t ws_size,
                              hipStream_t stream)
{
    const float* hidden  = (const float*)d_in[0];
    const float* enc     = (const float*)d_in[1];
    const float* refp    = (const float*)d_in[2];
    const float* w_value = (const float*)d_in[3];
    const float* b_value = (const float*)d_in[4];
    const float* w_off   = (const float*)d_in[5];
    const float* b_off   = (const float*)d_in[6];
    const float* w_attn  = (const float*)d_in[7];
    const float* b_attn  = (const float*)d_in[8];
    const float* w_out   = (const float*)d_in[9];
    const float* b_out   = (const float*)d_in[10];

    // ws layout: value 68,812,800 | sampled 2,457,600 | attnw 1,843,200 |
    // locw 3,686,400 | wv_swz 131,072 | wo_swz 131,072 | wp_swz 147,456
    char* ws = (char*)d_ws;
    unsigned short* value   = (unsigned short*)ws;
    unsigned short* sampled = (unsigned short*)(ws + 68812800);
    float*          attnw   = (float*)(ws + 71270400);
    float*          locw    = (float*)(ws + 73113600);
    short8*         wv_swz  = (short8*)(ws + 76800000);
    short8*         wo_swz  = (short8*)(ws + 76931072);
    short8*         wp_swz  = (short8*)(ws + 77062144);

    prep_kernel<<<100, 256, 0, stream>>>(w_value, w_out, w_off, w_attn,        // K0
                                         wv_swz, wo_swz, wp_swz);
    gemm_nt<false, true><<<2100, 256, 0, stream>>>(enc, wv_swz, b_value,       // K1
                                                   value);
    proj_gemm<<<150, 256, 0, stream>>>(hidden, wp_swz, b_off, b_attn,          // K2
                                       refp, attnw, locw);
    sample_kernel<<<4800, 256, 0, stream>>>(value, attnw, locw, sampled);      // K3
    gemm_nt<true, false><<<75, 256, 0, stream>>>(sampled, wo_swz, b_out,       // K4
                                                 d_out);
}

// Round 8
// 296.593 us; speedup vs baseline: 1.1974x; 1.0071x over previous
//
#include <hip/hip_runtime.h>

// RT-DETRv2 multiscale deformable attention, MI355X/gfx950.
// B=16, Q=300, S=8400 (80x80+40x40+20x20), D=256, H=8, HD=32, L=3, P=4, LP=12.
// Inputs fp32, output fp32 (verified; absmax 1.2e-3 vs thr 2.7e-3).
//
//   K0 prep:      pre-swizzle weights fp32->bf16 into B-fragment order
//   K1 gemm128:   value = enc @ w_value^T + b     -> ws bf16 [b][s][h][32]
//                 (128x128 block tile, 64x64 wave tile, 4x4 frag reuse:
//                  8 ds_read per 16 MFMA — halves LDS-pipe time vs R4-R7)
//   K2 proj_gemm: MFMA logits + fused softmax/loc -> ws attnw/locw fp32
//   K3 sample:    precomputed-corner gather + sum -> ws sampled bf16
//   K4 gemm_nt:   out = sampled @ w_out^T + b_out -> d_out fp32
//
// Measured laws so far:
//  - acc > 16 f32x4/wave (RPW=2: 276 regs) -> 1 wave/SIMD -> 83->121/137 us. Never.
//  - 16 ds_read:16 MFMA wave shape -> ~84 us regardless of barrier scheme
//    (R4/R6/R7 all ~84): LDS-pipe + latency bound, not barrier bound.

typedef __attribute__((ext_vector_type(8))) short short8;   // MFMA A/B frag (8 bf16)
typedef __attribute__((ext_vector_type(4))) float f32x4;    // MFMA accumulator

__device__ __forceinline__ unsigned short f2bf(float f) {   // fp32 -> bf16 RTNE
    union { float f; unsigned int i; } v; v.f = f;
    unsigned int r = v.i + 0x7FFFu + ((v.i >> 16) & 1u);
    return (unsigned short)(r >> 16);
}
__device__ __forceinline__ float bf2f(unsigned short u) {
    union { unsigned int i; float f; } v;
    v.i = ((unsigned int)u) << 16;
    return v.f;
}
__device__ __forceinline__ short8 cvt8(const float* p) {
    f32x4 x = *(const f32x4*)p;
    f32x4 y = *(const f32x4*)(p + 4);
    short8 r;
#pragma unroll
    for (int q = 0; q < 4; ++q) {
        r[q]     = (short)f2bf(x[q]);
        r[q + 4] = (short)f2bf(y[q]);
    }
    return r;
}
__device__ __forceinline__ void barrier_lgkm() {
    asm volatile("s_waitcnt lgkmcnt(0)\n\ts_barrier" ::: "memory");
}

// ---- K0: pre-swizzle weights into B-fragment order (bf16) ------------------
// Slot s = kcb*1024 + tile*64 + fragLane holds
// W[n = tile*16 + (fl&15)][kcb*32 + (fl>>4)*8 .. +8).  Proj W: 18 n-tiles
// (288 rows = w_off ++ w_attn), 1152 slots/kcb.
__global__ __launch_bounds__(256) void prep_kernel(
    const float* __restrict__ wv, const float* __restrict__ wo,
    const float* __restrict__ w_off, const float* __restrict__ w_attn,
    short8* __restrict__ wv_s, short8* __restrict__ wo_s, short8* __restrict__ wp_s)
{
    const int blk = blockIdx.x, tid = threadIdx.x;
    if (blk < 64) {
        const float* W = (blk < 32) ? wv : wo;
        short8* out    = (blk < 32) ? wv_s : wo_s;
        int s   = ((blk & 31) << 8) + tid;
        int kcb = s >> 10, sl = s & 1023;
        int n = ((sl >> 6) << 4) + (sl & 15);
        int k = (kcb << 5) + (((sl >> 4) & 3) << 3);
        out[s] = cvt8(W + n * 256 + k);
    } else {
        int s   = ((blk - 64) << 8) + tid;
        int kcb = s / 1152, sl = s - kcb * 1152;
        int n = ((sl >> 6) << 4) + (sl & 15);
        int k = (kcb << 5) + (((sl >> 4) & 3) << 3);
        const float* p = (n < 192) ? (w_off + (size_t)n * 256 + k)
                                   : (w_attn + (size_t)(n - 192) * 256 + k);
        wp_s[s] = cvt8(p);
    }
}

// ---- K1: C[M x 256] = A[M x 256] @ W^T + bias, 128x128 tiles ---------------
// Grid: (M/128)*2 blocks; blockIdx>>1 = row block, &1 = col half (128 cols).
// 4 waves = 2x2 quadrants of 64x64. Per kcb: stage A-tile (fp32->bf16, frag
// order) + B-tile (copy from pre-swizzled W) into LDS; each wave reads 4 A +
// 4 B frags (8 ds_read_b128) and issues 16 MFMA. acc[4][4] = 64 AGPR.
__global__ __launch_bounds__(256) void gemm128(
    const float* __restrict__ A,
    const short8* __restrict__ Wswz,
    const float* __restrict__ bias,
    unsigned short* __restrict__ C)
{
    __shared__ short8 lb[1024];   // 16 KiB: A slots [0,512), B slots [512,1024)
    const int tid  = threadIdx.x;
    const int wave = tid >> 6;
    const int lane = tid & 63;
    const int row0 = (blockIdx.x >> 1) * 128;
    const int colt = blockIdx.x & 1;            // which 128-col half
    const int mq   = wave >> 1;                 // wave quadrant
    const int nq   = wave & 1;

    f32x4 acc[4][4];
#pragma unroll
    for (int i = 0; i < 4; ++i)
#pragma unroll
        for (int j = 0; j < 4; ++j) acc[i][j] = (f32x4){0.f, 0.f, 0.f, 0.f};

    // staging indices for this thread's 4 slots (2 A, 2 B)
    const int sa0 = tid, sa1 = tid + 256;       // A slots
    const int am0 = row0 + ((sa0 >> 6) << 4) + (sa0 & 15);
    const int ak0 = ((sa0 >> 4) & 3) << 3;
    const int am1 = row0 + ((sa1 >> 6) << 4) + (sa1 & 15);
    const int ak1 = ((sa1 >> 4) & 3) << 3;

    for (int kcb = 0; kcb < 8; ++kcb) {
        const int kc = kcb << 5;
        barrier_lgkm();
        // A tile: 512 slots in fragment order
        lb[sa0] = cvt8(A + (size_t)am0 * 256 + kc + ak0);
        lb[sa1] = cvt8(A + (size_t)am1 * 256 + kc + ak1);
        // B tile: contiguous 512-slot copy of this col-half's 8 n-tiles
        const short8* wsrc = Wswz + (kcb << 10) + (colt << 9);
        lb[512 + tid]       = wsrc[tid];
        lb[768 + tid]       = wsrc[tid + 256];
        barrier_lgkm();

        short8 af[4], bf[4];
#pragma unroll
        for (int i = 0; i < 4; ++i) af[i] = lb[((mq << 2) + i) * 64 + lane];
#pragma unroll
        for (int j = 0; j < 4; ++j) bf[j] = lb[512 + ((nq << 2) + j) * 64 + lane];
#pragma unroll
        for (int i = 0; i < 4; ++i)
#pragma unroll
            for (int j = 0; j < 4; ++j)
                acc[i][j] = __builtin_amdgcn_mfma_f32_16x16x32_bf16(af[i], bf[j], acc[i][j], 0, 0, 0);
    }

    // epilogue: D row = row0 + (mq*4+i)*16 + (lane>>4)*4 + r,
    //           col = colt*128 + (nq*4+j)*16 + (lane&15)
    const int ncol = lane & 15;
    const int rsub = (lane >> 4) << 2;
#pragma unroll
    for (int i = 0; i < 4; ++i) {
        const int rb = row0 + ((mq << 2) + i) * 16 + rsub;
#pragma unroll
        for (int j = 0; j < 4; ++j) {
            const int n = (colt << 7) + ((nq << 2) + j) * 16 + ncol;
            const float bv = bias[n];
#pragma unroll
            for (int r = 0; r < 4; ++r)
                C[(size_t)(rb + r) * 256 + n] = f2bf(acc[i][j][r] + bv);
        }
    }
}

// ---- K4: small-M GEMM (R7 structure, M=4800) -------------------------------
template <bool A_BF16, bool OUT_BF16>
__global__ __launch_bounds__(256) void gemm_nt(
    const void* __restrict__ Av,
    const short8* __restrict__ Wswz,
    const float* __restrict__ bias,
    void* __restrict__ Cv)
{
    __shared__ short8 lb[2048];
    const int tid  = threadIdx.x;
    const int wave = tid >> 6;
    const int lane = tid & 63;
    const int row0 = blockIdx.x * 64 + wave * 16;

    f32x4 acc[16];
#pragma unroll
    for (int t = 0; t < 16; ++t) acc[t] = (f32x4){0.f, 0.f, 0.f, 0.f};

    const int am = row0 + (lane & 15);
    const int kq = (lane >> 4) << 3;

    const unsigned short* Ab = (const unsigned short*)Av;
    const float*          Af = (const float*)Av;

    short8 acur[2], anext[2];
#pragma unroll
    for (int kk = 0; kk < 2; ++kk) {
        if (A_BF16) acur[kk] = *(const short8*)(Ab + (size_t)am * 256 + (kk << 5) + kq);
        else        acur[kk] = cvt8(Af + (size_t)am * 256 + (kk << 5) + kq);
    }

    for (int st = 0; st < 4; ++st) {
        barrier_lgkm();
#pragma unroll
        for (int i = 0; i < 8; ++i) {
            int s = tid + (i << 8);
            lb[s] = Wswz[(st << 11) + s];
        }
        barrier_lgkm();

        if (st < 3) {
            int kc = (st + 1) << 6;
#pragma unroll
            for (int kk = 0; kk < 2; ++kk) {
                if (A_BF16) anext[kk] = *(const short8*)(Ab + (size_t)am * 256 + kc + (kk << 5) + kq);
                else        anext[kk] = cvt8(Af + (size_t)am * 256 + kc + (kk << 5) + kq);
            }
        }

#pragma unroll
        for (int t = 0; t < 16; ++t) {
            short8 b0 = lb[t * 64 + lane];
            acc[t] = __builtin_amdgcn_mfma_f32_16x16x32_bf16(acur[0], b0, acc[t], 0, 0, 0);
            short8 b1 = lb[1024 + t * 64 + lane];
            acc[t] = __builtin_amdgcn_mfma_f32_16x16x32_bf16(acur[1], b1, acc[t], 0, 0, 0);
        }
        acur[0] = anext[0];
        acur[1] = anext[1];
    }

    const int ncol = lane & 15;
    const int rb   = row0 + ((lane >> 4) << 2);
#pragma unroll
    for (int t = 0; t < 16; ++t) {
        int n = (t << 4) + ncol;
        float bv = bias[n];
#pragma unroll
        for (int r = 0; r < 4; ++r) {
            float v = acc[t][r] + bv;
            if (OUT_BF16)
                ((unsigned short*)Cv)[(size_t)(rb + r) * 256 + n] = f2bf(v);
            else
                ((float*)Cv)[(size_t)(rb + r) * 256 + n] = v;
        }
    }
}

// ---- K2: proj logits (MFMA) + fused softmax + sample locations -------------
#define LGS 296   // padded LDS row stride (floats)
__global__ __launch_bounds__(256) void proj_gemm(
    const float* __restrict__ hidden,
    const short8* __restrict__ Wswz,
    const float* __restrict__ b_off, const float* __restrict__ b_attn,
    const float* __restrict__ refp,
    float* __restrict__ attnw, float* __restrict__ locw)
{
    __shared__ char smem[32 * LGS * 4];
    short8* lb = (short8*)smem;
    float*  lg = (float*)smem;

    const int tid  = threadIdx.x;
    const int wave = tid >> 6;
    const int lane = tid & 63;
    const int rq0  = blockIdx.x * 32;
    const int rg   = wave >> 1;
    const int ts   = (wave & 1) * 9;
    const int row0 = rq0 + rg * 16;

    f32x4 acc[9];
#pragma unroll
    for (int t = 0; t < 9; ++t) acc[t] = (f32x4){0.f, 0.f, 0.f, 0.f};

    const int am = row0 + (lane & 15);
    const int kq = (lane >> 4) << 3;

    for (int kcb = 0; kcb < 8; ++kcb) {
        __syncthreads();
#pragma unroll
        for (int i = 0; i < 5; ++i) {
            int s = tid + (i << 8);
            if (s < 1152) lb[s] = Wswz[kcb * 1152 + s];
        }
        __syncthreads();

        short8 a = cvt8(hidden + (size_t)am * 256 + (kcb << 5) + kq);
#pragma unroll
        for (int t = 0; t < 9; ++t)
            acc[t] = __builtin_amdgcn_mfma_f32_16x16x32_bf16(a, lb[(ts + t) * 64 + lane], acc[t], 0, 0, 0);
    }

    __syncthreads();
    const int ncol = lane & 15;
    const int rb   = rg * 16 + ((lane >> 4) << 2);
#pragma unroll
    for (int t = 0; t < 9; ++t) {
        int n = (ts + t) * 16 + ncol;
        float bv = (n < 192) ? b_off[n] : b_attn[n - 192];
#pragma unroll
        for (int r = 0; r < 4; ++r)
            lg[(rb + r) * LGS + n] = acc[t][r] + bv;
    }
    __syncthreads();

    {   // softmax: 32 rows x 8 heads, one per thread
        int r = tid >> 3, h = tid & 7;
        const float* lrow = lg + r * LGS + 192 + h * 12;
        float m = -1e30f;
#pragma unroll
        for (int p = 0; p < 12; ++p) m = fmaxf(m, lrow[p]);
        float e[12], sum = 0.f;
#pragma unroll
        for (int p = 0; p < 12; ++p) { e[p] = __expf(lrow[p] - m); sum += e[p]; }
        float inv = 1.f / sum;
        float* ao = attnw + (size_t)(rq0 + r) * 96 + h * 12;
#pragma unroll
        for (int p = 0; p < 12; ++p) ao[p] = e[p] * inv;
    }
    if (tid < 192) {   // loc = ref_xy + logit*0.125*ref_wh
        int xy = tid & 1;
        for (int r = 0; r < 32; ++r) {
            int rq = rq0 + r;
            float rc  = refp[(size_t)rq * 4 + xy];
            float rwh = refp[(size_t)rq * 4 + 2 + xy];
            locw[(size_t)rq * 192 + tid] = rc + lg[r * LGS + tid] * 0.125f * rwh;
        }
    }
}

// ---- K3: deformable bilinear sampling --------------------------------------
__global__ __launch_bounds__(256) void sample_kernel(
    const unsigned short* __restrict__ value,   // bf16 [b][s][h][32]
    const float* __restrict__ attnw, const float* __restrict__ locw,
    unsigned short* __restrict__ sampled)       // bf16 [rq][256]
{
    const int rq  = blockIdx.x;
    const int b   = rq / 300;
    const int tid = threadIdx.x;

    __shared__ int4   soff[96];
    __shared__ float4 swt[96];

    if (tid < 96) {
        int h = tid / 12, lp = tid - h * 12;
        int l = lp >> 2;
        int Wl = (l == 0) ? 80 : (l == 1) ? 40 : 20;        // H == W per level
        int s0 = (l == 0) ? 0  : (l == 1) ? 6400 : 8000;
        float lx = locw[(size_t)rq * 192 + h * 24 + lp * 2];
        float ly = locw[(size_t)rq * 192 + h * 24 + lp * 2 + 1];
        float aw = attnw[(size_t)rq * 96 + h * 12 + lp];
        float gx = lx * (float)Wl - 0.5f;
        float gy = ly * (float)Wl - 0.5f;
        float x0f = floorf(gx), y0f = floorf(gy);
        int   x0 = (int)x0f,   y0 = (int)y0f;
        float wx1 = gx - x0f, wx0 = 1.f - wx1;
        float wy1 = gy - y0f, wy0 = 1.f - wy1;
        int4 of; float4 wt;
#pragma unroll
        for (int j = 0; j < 4; ++j) {
            int x = x0 + (j & 1), y = y0 + (j >> 1);
            bool ok = (x >= 0) & (x < Wl) & (y >= 0) & (y < Wl);
            int idx = ok ? (((b * 8400 + s0 + y * Wl + x) * 8 + h) * 32) : 0;
            float w = ok ? aw * ((j & 1) ? wx1 : wx0) * ((j >> 1) ? wy1 : wy0) : 0.f;
            ((int*)&of)[j] = idx;
            ((float*)&wt)[j] = w;
        }
        soff[tid] = of;
        swt[tid]  = wt;
    }
    __syncthreads();

    const int h = tid >> 5, c = tid & 31;
    float acc = 0.f;
#pragma unroll
    for (int lp = 0; lp < 12; ++lp) {
        int idx = h * 12 + lp;
        int4   of = soff[idx];
        float4 wt = swt[idx];
        acc += wt.x * bf2f(value[of.x + c]);
        acc += wt.y * bf2f(value[of.y + c]);
        acc += wt.z * bf2f(value[of.z + c]);
        acc += wt.w * bf2f(value[of.w + c]);
    }
    sampled[(size_t)rq * 256 + tid] = f2bf(acc);
}

extern "C" void kernel_launch(void* const* d_in, const int* in_sizes, int n_in,
                              void* d_out, int out_size, void* d_ws, size_t ws_size,
                              hipStream_t stream)
{
    const float* hidden  = (const float*)d_in[0];
    const float* enc     = (const float*)d_in[1];
    const float* refp    = (const float*)d_in[2];
    const float* w_value = (const float*)d_in[3];
    const float* b_value = (const float*)d_in[4];
    const float* w_off   = (const float*)d_in[5];
    const float* b_off   = (const float*)d_in[6];
    const float* w_attn  = (const float*)d_in[7];
    const float* b_attn  = (const float*)d_in[8];
    const float* w_out   = (const float*)d_in[9];
    const float* b_out   = (const float*)d_in[10];

    // ws layout: value 68,812,800 | sampled 2,457,600 | attnw 1,843,200 |
    // locw 3,686,400 | wv_swz 131,072 | wo_swz 131,072 | wp_swz 147,456
    char* ws = (char*)d_ws;
    unsigned short* value   = (unsigned short*)ws;
    unsigned short* sampled = (unsigned short*)(ws + 68812800);
    float*          attnw   = (float*)(ws + 71270400);
    float*          locw    = (float*)(ws + 73113600);
    short8*         wv_swz  = (short8*)(ws + 76800000);
    short8*         wo_swz  = (short8*)(ws + 76931072);
    short8*         wp_swz  = (short8*)(ws + 77062144);

    prep_kernel<<<100, 256, 0, stream>>>(w_value, w_out, w_off, w_attn,        // K0
                                         wv_swz, wo_swz, wp_swz);
    gemm128<<<2100, 256, 0, stream>>>(enc, wv_swz, b_value, value);            // K1
    proj_gemm<<<150, 256, 0, stream>>>(hidden, wp_swz, b_off, b_attn,          // K2
                                       refp, attnw, locw);
    sample_kernel<<<4800, 256, 0, stream>>>(value, attnw, locw, sampled);      // K3
    gemm_nt<true, false><<<75, 256, 0, stream>>>(sampled, wo_swz, b_out,       // K4
                                                 d_out);
}